// Round 10
// baseline (41492.514 us; speedup 1.0000x reference)
//
#include <hip/hip_runtime.h>
#include <hip/hip_bf16.h>

#define N_NODES 12288
#define D 256
#define NE 196608
#define TOPK 4
#define TM 32
#define TN 32
#define NSPLIT 2
#define CPS (N_NODES / NSPLIT)   // 6144 cols per split
#define MAXDEG 256
// MEASURED (rounds 0-9, all bit-consistent): harness reads d_out as FLOAT32,
// identity layout: [ h 3145728 | top_idx 49152 | rows 49152 | top_vals 49152 ].

// ---------------- insert helpers (top-4, descending) ----------------
__device__ __forceinline__ void ins4(float v, int id, float tv[TOPK], int ti[TOPK]) {
  if (v > tv[3]) {
    tv[3] = v; ti[3] = id;
    if (tv[3] > tv[2]) {
      float a = tv[2]; tv[2] = tv[3]; tv[3] = a; int b = ti[2]; ti[2] = ti[3]; ti[3] = b;
      if (tv[2] > tv[1]) {
        float a2 = tv[1]; tv[1] = tv[2]; tv[2] = a2; int b2 = ti[1]; ti[1] = ti[2]; ti[2] = b2;
        if (tv[1] > tv[0]) {
          float a3 = tv[0]; tv[0] = tv[1]; tv[1] = a3; int b3 = ti[0]; ti[0] = ti[1]; ti[1] = b3;
        }
      }
    }
  }
}

__device__ __forceinline__ void ins4tie(float v, int id, float tv[TOPK], int ti[TOPK]) {
  if ((v > tv[3]) || (v == tv[3] && id < ti[3])) {
    tv[3] = v; ti[3] = id;
    if ((tv[3] > tv[2]) || (tv[3] == tv[2] && ti[3] < ti[2])) {
      float a = tv[2]; tv[2] = tv[3]; tv[3] = a; int b = ti[2]; ti[2] = ti[3]; ti[3] = b;
      if ((tv[2] > tv[1]) || (tv[2] == tv[1] && ti[2] < ti[1])) {
        float a2 = tv[1]; tv[1] = tv[2]; tv[2] = a2; int b2 = ti[1]; ti[1] = ti[2]; ti[2] = b2;
        if ((tv[1] > tv[0]) || (tv[1] == tv[0] && ti[1] < ti[0])) {
          float a3 = tv[0]; tv[0] = tv[1]; tv[1] = a3; int b3 = ti[0]; ti[0] = ti[1]; ti[1] = b3;
        }
      }
    }
  }
}

// ---------------- K1: XW = x @ W ----------------
__global__ __launch_bounds__(256) void k_xw(const float* __restrict__ X,
                                            const float* __restrict__ W,
                                            float* __restrict__ XW) {
  __shared__ float sA[16][65];
  __shared__ float sB[16][65];
  const int tid = threadIdx.x;
  const int ty = tid >> 4, tx = tid & 15;
  const int by = blockIdx.x, bx = blockIdx.y;
  float acc[4][4] = {};
  for (int kk = 0; kk < D; kk += 16) {
    {
      int m = tid >> 2;
      int kq = (tid & 3) << 2;
      const float4 av = *(const float4*)&X[(size_t)(by * 64 + m) * D + kk + kq];
      sA[kq + 0][m] = av.x; sA[kq + 1][m] = av.y; sA[kq + 2][m] = av.z; sA[kq + 3][m] = av.w;
    }
    {
      int r = tid >> 4;
      int c = (tid & 15) << 2;
      const float4 bv = *(const float4*)&W[(size_t)(kk + r) * D + bx * 64 + c];
      sB[r][c + 0] = bv.x; sB[r][c + 1] = bv.y; sB[r][c + 2] = bv.z; sB[r][c + 3] = bv.w;
    }
    __syncthreads();
#pragma unroll
    for (int k = 0; k < 16; ++k) {
      float a[4], b[4];
#pragma unroll
      for (int i = 0; i < 4; i++) a[i] = sA[k][ty + 16 * i];
#pragma unroll
      for (int j = 0; j < 4; j++) b[j] = sB[k][tx + 16 * j];
#pragma unroll
      for (int i = 0; i < 4; i++)
#pragma unroll
        for (int j = 0; j < 4; j++) acc[i][j] = fmaf(a[i], b[j], acc[i][j]);
    }
    __syncthreads();
  }
#pragma unroll
  for (int i = 0; i < 4; i++)
#pragma unroll
    for (int j = 0; j < 4; j++)
      XW[(size_t)(by * 64 + ty + 16 * i) * D + bx * 64 + tx + 16 * j] = acc[i][j];
}

// ---------------- K2: in-degree histogram ----------------
__global__ void k_deg(const int* __restrict__ row, int* __restrict__ deg) {
  int e = blockIdx.x * blockDim.x + threadIdx.x;
  if (e < NE) {
    unsigned r = (unsigned)row[e];
    if (r < N_NODES) atomicAdd(&deg[r], 1);
  }
}

// ---------------- K3: exclusive scan + dinv ----------------
__global__ __launch_bounds__(256) void k_scan(const int* __restrict__ deg,
                                              int* __restrict__ row_start,
                                              float* __restrict__ dinv) {
  __shared__ int part[256];
  const int tid = threadIdx.x;
  const int L = N_NODES / 256;  // 48
  const int base = tid * L;
  int s = 0;
  for (int i = 0; i < L; i++) s += deg[base + i];
  part[tid] = s;
  __syncthreads();
  for (int off = 1; off < 256; off <<= 1) {
    int v = (tid >= off) ? part[tid - off] : 0;
    __syncthreads();
    part[tid] += v;
    __syncthreads();
  }
  int run = part[tid] - s;
  for (int i = 0; i < L; i++) {
    int d = deg[base + i];
    row_start[base + i] = run;
    dinv[base + i] = 1.0f / sqrtf((float)(d + 1));
    run += d;
  }
}

// ---------------- K4: CSR fill ----------------
__global__ void k_fill(const int* __restrict__ row, const int* __restrict__ col,
                       const int* __restrict__ row_start, int* __restrict__ cursor,
                       int* __restrict__ ecol, int* __restrict__ eeid) {
  int e = blockIdx.x * blockDim.x + threadIdx.x;
  if (e >= NE) return;
  unsigned r = (unsigned)row[e];
  if (r >= N_NODES) return;
  int p = atomicAdd(&cursor[r], 1);
  int slot = row_start[r] + p;
  if ((unsigned)slot >= NE) return;
  unsigned c = (unsigned)col[e];
  if (c >= N_NODES) c = 0;
  ecol[slot] = (int)c;
  eeid[slot] = e;
}

// ---------------- K5: aggregation (eid-sorted -> deterministic); h -> d_out ------
__global__ __launch_bounds__(256) void k_agg(const float* __restrict__ XW,
                                             const float* __restrict__ bias,
                                             const int* __restrict__ deg,
                                             const int* __restrict__ row_start,
                                             const int* __restrict__ ecol,
                                             const int* __restrict__ eeid,
                                             const float* __restrict__ dinv,
                                             float* __restrict__ h_out,
                                             float* __restrict__ sq) {
  __shared__ int sc[MAXDEG];
  __shared__ int se[MAXDEG];
  __shared__ float snorm[MAXDEG];
  __shared__ float red[256];
  const int i = blockIdx.x;
  const int tid = threadIdx.x;
  int cnt = deg[i];
  if (cnt > MAXDEG) cnt = MAXDEG;
  if (cnt < 0) cnt = 0;
  const int st = row_start[i];
  for (int t = tid; t < cnt; t += 256) {
    unsigned cc = (unsigned)ecol[st + t];
    sc[t] = (cc < N_NODES) ? (int)cc : 0;
    se[t] = eeid[st + t];
  }
  __syncthreads();
  if (tid == 0) {  // insertion sort by original edge id
    for (int a = 1; a < cnt; ++a) {
      int ce = se[a], cc = sc[a];
      int bp = a - 1;
      while (bp >= 0 && se[bp] > ce) { se[bp + 1] = se[bp]; sc[bp + 1] = sc[bp]; --bp; }
      se[bp + 1] = ce; sc[bp + 1] = cc;
    }
  }
  __syncthreads();
  const float di = dinv[i];
  for (int t = tid; t < cnt; t += 256) snorm[t] = __fmul_rn(di, dinv[sc[t]]);
  __syncthreads();
  float acc = 0.0f;
  for (int t = 0; t < cnt; ++t) {
    float v = XW[(size_t)sc[t] * D + tid];
    acc = __fadd_rn(acc, __fmul_rn(v, snorm[t]));
  }
  acc = __fadd_rn(acc, __fmul_rn(XW[(size_t)i * D + tid], __fmul_rn(di, di)));  // self loop last
  acc = __fadd_rn(acc, bias[tid]);
  h_out[(size_t)i * D + tid] = acc;   // h lives directly in d_out[0 : N*D)
  red[tid] = __fmul_rn(acc, acc);
  __syncthreads();
  for (int off = 128; off > 0; off >>= 1) {
    if (tid < off) red[tid] = __fadd_rn(red[tid], red[tid + off]);
    __syncthreads();
  }
  if (tid == 0) sq[i] = red[0];
}

// ---------------- K6: fused d2 + gumbel + per-row top-4 ----------------
__global__ __launch_bounds__(256) void k_fused(const float* __restrict__ h,
                                               const float* __restrict__ sq,
                                               const float* __restrict__ q,
                                               const float* __restrict__ tempP,
                                               float* __restrict__ cval,
                                               int* __restrict__ cidx) {
  __shared__ float4 sA4[TM * 64];
  __shared__ float4 sB4[TN * 64];
  const int tid = threadIdx.x;
  const int trow = tid >> 5;
  const int tcol = tid & 31;
  const int row0 = blockIdx.x * TM;
  const int split = blockIdx.y;
  const int c0 = split * CPS;
  const float T = tempP[0];

  for (int t = 0; t < 8; ++t) {
    int fi = t * 256 + tid;
    int row = fi >> 6, k4 = fi & 63;
    sA4[fi] = *(const float4*)&h[(size_t)(row0 + row) * D + k4 * 4];
  }
  float sqr[4];
#pragma unroll
  for (int i = 0; i < 4; i++) sqr[i] = sq[row0 + trow * 4 + i];

  float tv[4][TOPK];
  int ti[4][TOPK];
#pragma unroll
  for (int i = 0; i < 4; i++)
#pragma unroll
    for (int k = 0; k < TOPK; k++) { tv[i][k] = -3.0e38f; ti[i][k] = 0; }

  for (int ct = c0; ct < c0 + CPS; ct += TN) {
    __syncthreads();
    for (int t = 0; t < 8; ++t) {
      int fi = t * 256 + tid;
      int col = fi >> 6, k4 = fi & 63;
      sB4[col * 64 + (k4 ^ (col & 7))] = *(const float4*)&h[(size_t)(ct + col) * D + k4 * 4];
    }
    __syncthreads();

    const int c = ct + tcol;
    const float sqc = sq[c];
    float qv[4];
#pragma unroll
    for (int i = 0; i < 4; i++)
      qv[i] = q[(size_t)(row0 + trow * 4 + i) * N_NODES + c];

    float4 acc[4];
#pragma unroll
    for (int i = 0; i < 4; i++) acc[i] = make_float4(0.f, 0.f, 0.f, 0.f);
#pragma unroll
    for (int k4 = 0; k4 < 64; ++k4) {
      const float4 b = sB4[tcol * 64 + (k4 ^ (tcol & 7))];
#pragma unroll
      for (int i = 0; i < 4; i++) {
        const float4 a = sA4[(trow * 4 + i) * 64 + k4];
        acc[i].x = fmaf(a.x, b.x, acc[i].x);
        acc[i].y = fmaf(a.y, b.y, acc[i].y);
        acc[i].z = fmaf(a.z, b.z, acc[i].z);
        acc[i].w = fmaf(a.w, b.w, acc[i].w);
      }
    }

#pragma unroll
    for (int i = 0; i < 4; i++) {
      float dot = __fadd_rn(__fadd_rn(acc[i].x, acc[i].y), __fadd_rn(acc[i].z, acc[i].w));
      float s2 = __fadd_rn(sqr[i], sqc);
      float d2 = fmaxf(__fsub_rn(s2, __fmul_rn(2.0f, dot)), 0.0f);
      float lp = -__fmul_rn(T, d2);
      float gg = logf(-logf(__fadd_rn(qv[i], 1e-8f)));
      ins4(__fsub_rn(lp, gg), c, tv[i], ti[i]);
    }
  }

  // butterfly merge across the 32 column-lanes
#pragma unroll
  for (int i = 0; i < 4; i++) {
#pragma unroll
    for (int m = 1; m < 32; m <<= 1) {
      float ov[TOPK]; int oi[TOPK];
#pragma unroll
      for (int k = 0; k < TOPK; k++) {
        ov[k] = __shfl_xor(tv[i][k], m, 32);
        oi[k] = __shfl_xor(ti[i][k], m, 32);
      }
#pragma unroll
      for (int k = 0; k < TOPK; k++) ins4tie(ov[k], oi[k], tv[i], ti[i]);
    }
  }
  if (tcol == 0) {
#pragma unroll
    for (int i = 0; i < 4; i++)
#pragma unroll
      for (int k = 0; k < TOPK; k++) {
        cval[((size_t)(row0 + trow * 4 + i) * NSPLIT + split) * TOPK + k] = tv[i][k];
        cidx[((size_t)(row0 + trow * 4 + i) * NSPLIT + split) * TOPK + k] = ti[i][k];
      }
  }
}

// ---------------- K7: merge splits, write edges + top_vals as FLOAT32 ----------
__global__ __launch_bounds__(256) void k_merge(const float* __restrict__ cval,
                                               const int* __restrict__ cidx,
                                               float* __restrict__ out_idx,
                                               float* __restrict__ out_rows,
                                               float* __restrict__ out_vals) {
  int r = blockIdx.x * blockDim.x + threadIdx.x;
  if (r >= N_NODES) return;
  float bv[TOPK];
  int bi[TOPK];
#pragma unroll
  for (int k = 0; k < TOPK; k++) { bv[k] = -3.0e38f; bi[k] = 0; }
  for (int t = 0; t < NSPLIT * TOPK; t++)
    ins4tie(cval[(size_t)r * NSPLIT * TOPK + t], cidx[(size_t)r * NSPLIT * TOPK + t], bv, bi);
#pragma unroll
  for (int k = 0; k < TOPK; k++) {
    out_idx[r * TOPK + k] = (float)bi[k];
    out_rows[r * TOPK + k] = (float)r;
    out_vals[r * TOPK + k] = bv[k];
  }
}

// ---------------- launcher ----------------
extern "C" void kernel_launch(void* const* d_in, const int* in_sizes, int n_in,
                              void* d_out, int out_size, void* d_ws, size_t ws_size,
                              hipStream_t stream) {
  const float* x = nullptr;     // 3145728
  const float* W = nullptr;     // 65536
  const float* b = nullptr;     // 256
  const float* temp = nullptr;  // 1
  const float* q = nullptr;     // 150994944
  const int* ei = nullptr;      // 393216
  for (int i = 0; i < n_in; ++i) {
    switch (in_sizes[i]) {
      case 3145728:   x = (const float*)d_in[i]; break;
      case 65536:     W = (const float*)d_in[i]; break;
      case 256:       b = (const float*)d_in[i]; break;
      case 1:         temp = (const float*)d_in[i]; break;
      case 150994944: q = (const float*)d_in[i]; break;
      case 393216:    ei = (const int*)d_in[i]; break;
      default: break;
    }
  }
  if (!x || !W || !b || !temp || !q || !ei) return;

  float* out = (float*)d_out;
  float* out_h = out;                                  // [0, 3145728)
  float* out_idx = out + (size_t)N_NODES * D;          // [3145728, 3194880)
  float* out_rows = out_idx + (size_t)N_NODES * TOPK;  // [3194880, 3244032)
  float* out_vals = out_rows + (size_t)N_NODES * TOPK; // [3244032, 3293184)

  char* ws = (char*)d_ws;
  size_t off = 0;
  auto alloc = [&](size_t bytes) {
    char* p = ws + off;
    off += (bytes + 255) & ~(size_t)255;
    return p;
  };
  float* XW = (float*)alloc((size_t)N_NODES * D * 4);
  int* deg = (int*)alloc((size_t)N_NODES * 4);
  int* rs = (int*)alloc((size_t)N_NODES * 4);
  int* cur = (int*)alloc((size_t)N_NODES * 4);
  float* dinv = (float*)alloc((size_t)N_NODES * 4);
  float* sq = (float*)alloc((size_t)N_NODES * 4);
  int* ecol = (int*)alloc((size_t)NE * 4);
  int* eeid = (int*)alloc((size_t)NE * 4);
  float* cval = (float*)alloc((size_t)N_NODES * NSPLIT * TOPK * 4);
  int* cidx = (int*)alloc((size_t)N_NODES * NSPLIT * TOPK * 4);
  if (off > ws_size) return;

  hipMemsetAsync(deg, 0, (size_t)N_NODES * 4, stream);
  hipMemsetAsync(cur, 0, (size_t)N_NODES * 4, stream);

  k_xw<<<dim3(N_NODES / 64, D / 64), 256, 0, stream>>>(x, W, XW);
  k_deg<<<NE / 256, 256, 0, stream>>>(ei, deg);
  k_scan<<<1, 256, 0, stream>>>(deg, rs, dinv);
  k_fill<<<NE / 256, 256, 0, stream>>>(ei, ei + NE, rs, cur, ecol, eeid);
  k_agg<<<N_NODES, 256, 0, stream>>>(XW, b, deg, rs, ecol, eeid, dinv, out_h, sq);
  k_fused<<<dim3(N_NODES / TM, NSPLIT), 256, 0, stream>>>(out_h, sq, q, temp, cval, cidx);
  k_merge<<<N_NODES / 256, 256, 0, stream>>>(cval, cidx, out_idx, out_rows, out_vals);
}

// Round 11
// 2625.450 us; speedup vs baseline: 15.8040x; 15.8040x over previous
//
#include <hip/hip_runtime.h>
#include <hip/hip_bf16.h>

#define N_NODES 12288
#define D 256
#define NE 196608
#define TOPK 4
#define TM 32
#define TN 32
#define NSPLIT 2
#define CPS (N_NODES / NSPLIT)   // 6144 cols per split
#define MAXDEG 256
// MEASURED (rounds 0-9): harness reads d_out as FLOAT32, identity layout:
// [ h 3145728 | top_idx 49152 | rows 49152 | top_vals 49152 ].

// ---------------- insert helpers (top-4, descending) ----------------
__device__ __forceinline__ void ins4(float v, int id, float tv[TOPK], int ti[TOPK]) {
  if (v > tv[3]) {
    tv[3] = v; ti[3] = id;
    if (tv[3] > tv[2]) {
      float a = tv[2]; tv[2] = tv[3]; tv[3] = a; int b = ti[2]; ti[2] = ti[3]; ti[3] = b;
      if (tv[2] > tv[1]) {
        float a2 = tv[1]; tv[1] = tv[2]; tv[2] = a2; int b2 = ti[1]; ti[1] = ti[2]; ti[2] = b2;
        if (tv[1] > tv[0]) {
          float a3 = tv[0]; tv[0] = tv[1]; tv[1] = a3; int b3 = ti[0]; ti[0] = ti[1]; ti[1] = b3;
        }
      }
    }
  }
}

__device__ __forceinline__ void ins4tie(float v, int id, float tv[TOPK], int ti[TOPK]) {
  if ((v > tv[3]) || (v == tv[3] && id < ti[3])) {
    tv[3] = v; ti[3] = id;
    if ((tv[3] > tv[2]) || (tv[3] == tv[2] && ti[3] < ti[2])) {
      float a = tv[2]; tv[2] = tv[3]; tv[3] = a; int b = ti[2]; ti[2] = ti[3]; ti[3] = b;
      if ((tv[2] > tv[1]) || (tv[2] == tv[1] && ti[2] < ti[1])) {
        float a2 = tv[1]; tv[1] = tv[2]; tv[2] = a2; int b2 = ti[1]; ti[1] = ti[2]; ti[2] = b2;
        if ((tv[1] > tv[0]) || (tv[1] == tv[0] && ti[1] < ti[0])) {
          float a3 = tv[0]; tv[0] = tv[1]; tv[1] = a3; int b3 = ti[0]; ti[0] = ti[1]; ti[1] = b3;
        }
      }
    }
  }
}

// ---------------- K1: XW = x @ W ----------------
__global__ __launch_bounds__(256) void k_xw(const float* __restrict__ X,
                                            const float* __restrict__ W,
                                            float* __restrict__ XW) {
  __shared__ float sA[16][65];
  __shared__ float sB[16][65];
  const int tid = threadIdx.x;
  const int ty = tid >> 4, tx = tid & 15;
  const int by = blockIdx.x, bx = blockIdx.y;
  float acc[4][4] = {};
  for (int kk = 0; kk < D; kk += 16) {
    {
      int m = tid >> 2;
      int kq = (tid & 3) << 2;
      const float4 av = *(const float4*)&X[(size_t)(by * 64 + m) * D + kk + kq];
      sA[kq + 0][m] = av.x; sA[kq + 1][m] = av.y; sA[kq + 2][m] = av.z; sA[kq + 3][m] = av.w;
    }
    {
      int r = tid >> 4;
      int c = (tid & 15) << 2;
      const float4 bv = *(const float4*)&W[(size_t)(kk + r) * D + bx * 64 + c];
      sB[r][c + 0] = bv.x; sB[r][c + 1] = bv.y; sB[r][c + 2] = bv.z; sB[r][c + 3] = bv.w;
    }
    __syncthreads();
#pragma unroll
    for (int k = 0; k < 16; ++k) {
      float a[4], b[4];
#pragma unroll
      for (int i = 0; i < 4; i++) a[i] = sA[k][ty + 16 * i];
#pragma unroll
      for (int j = 0; j < 4; j++) b[j] = sB[k][tx + 16 * j];
#pragma unroll
      for (int i = 0; i < 4; i++)
#pragma unroll
        for (int j = 0; j < 4; j++) acc[i][j] = fmaf(a[i], b[j], acc[i][j]);
    }
    __syncthreads();
  }
#pragma unroll
  for (int i = 0; i < 4; i++)
#pragma unroll
    for (int j = 0; j < 4; j++)
      XW[(size_t)(by * 64 + ty + 16 * i) * D + bx * 64 + tx + 16 * j] = acc[i][j];
}

// ---------------- K2: in-degree histogram ----------------
__global__ void k_deg(const int* __restrict__ row, int* __restrict__ deg) {
  int e = blockIdx.x * blockDim.x + threadIdx.x;
  if (e < NE) {
    unsigned r = (unsigned)row[e];
    if (r < N_NODES) atomicAdd(&deg[r], 1);
  }
}

// ---------------- K3: exclusive scan + dinv ----------------
__global__ __launch_bounds__(256) void k_scan(const int* __restrict__ deg,
                                              int* __restrict__ row_start,
                                              float* __restrict__ dinv) {
  __shared__ int part[256];
  const int tid = threadIdx.x;
  const int L = N_NODES / 256;  // 48
  const int base = tid * L;
  int s = 0;
  for (int i = 0; i < L; i++) s += deg[base + i];
  part[tid] = s;
  __syncthreads();
  for (int off = 1; off < 256; off <<= 1) {
    int v = (tid >= off) ? part[tid - off] : 0;
    __syncthreads();
    part[tid] += v;
    __syncthreads();
  }
  int run = part[tid] - s;
  for (int i = 0; i < L; i++) {
    int d = deg[base + i];
    row_start[base + i] = run;
    dinv[base + i] = 1.0f / sqrtf((float)(d + 1));
    run += d;
  }
}

// ---------------- K4: CSR fill ----------------
__global__ void k_fill(const int* __restrict__ row, const int* __restrict__ col,
                       const int* __restrict__ row_start, int* __restrict__ cursor,
                       int* __restrict__ ecol, int* __restrict__ eeid) {
  int e = blockIdx.x * blockDim.x + threadIdx.x;
  if (e >= NE) return;
  unsigned r = (unsigned)row[e];
  if (r >= N_NODES) return;
  int p = atomicAdd(&cursor[r], 1);
  int slot = row_start[r] + p;
  if ((unsigned)slot >= NE) return;
  unsigned c = (unsigned)col[e];
  if (c >= N_NODES) c = 0;
  ecol[slot] = (int)c;
  eeid[slot] = e;
}

// ---------------- K5: aggregation (eid-sorted -> deterministic); h -> d_out ------
__global__ __launch_bounds__(256) void k_agg(const float* __restrict__ XW,
                                             const float* __restrict__ bias,
                                             const int* __restrict__ deg,
                                             const int* __restrict__ row_start,
                                             const int* __restrict__ ecol,
                                             const int* __restrict__ eeid,
                                             const float* __restrict__ dinv,
                                             float* __restrict__ h_out,
                                             float* __restrict__ sq) {
  __shared__ int sc[MAXDEG];
  __shared__ int se[MAXDEG];
  __shared__ float snorm[MAXDEG];
  __shared__ float red[256];
  const int i = blockIdx.x;
  const int tid = threadIdx.x;
  int cnt = deg[i];
  if (cnt > MAXDEG) cnt = MAXDEG;
  if (cnt < 0) cnt = 0;
  const int st = row_start[i];
  for (int t = tid; t < cnt; t += 256) {
    unsigned cc = (unsigned)ecol[st + t];
    sc[t] = (cc < N_NODES) ? (int)cc : 0;
    se[t] = eeid[st + t];
  }
  __syncthreads();
  if (tid == 0) {  // insertion sort by original edge id
    for (int a = 1; a < cnt; ++a) {
      int ce = se[a], cc = sc[a];
      int bp = a - 1;
      while (bp >= 0 && se[bp] > ce) { se[bp + 1] = se[bp]; sc[bp + 1] = sc[bp]; --bp; }
      se[bp + 1] = ce; sc[bp + 1] = cc;
    }
  }
  __syncthreads();
  const float di = dinv[i];
  for (int t = tid; t < cnt; t += 256) snorm[t] = __fmul_rn(di, dinv[sc[t]]);
  __syncthreads();
  float acc = 0.0f;
  for (int t = 0; t < cnt; ++t) {
    float v = XW[(size_t)sc[t] * D + tid];
    acc = __fadd_rn(acc, __fmul_rn(v, snorm[t]));
  }
  acc = __fadd_rn(acc, __fmul_rn(XW[(size_t)i * D + tid], __fmul_rn(di, di)));  // self loop last
  acc = __fadd_rn(acc, bias[tid]);
  h_out[(size_t)i * D + tid] = acc;   // h lives directly in d_out[0 : N*D)
  red[tid] = __fmul_rn(acc, acc);
  __syncthreads();
  for (int off = 128; off > 0; off >>= 1) {
    if (tid < off) red[tid] = __fadd_rn(red[tid], red[tid + off]);
    __syncthreads();
  }
  if (tid == 0) sq[i] = red[0];
}

// ---------------- K6 v2: fused d2 + gumbel + top-4 (spill-free, T14 staged) -----
// Fix vs round 10 (VGPR=256, 82 GB scratch writes, VALUBusy 3.6%):
//  * k4 loop: #pragma unroll 4 (was full 64x unroll -> register explosion)
//  * __launch_bounds__(256,2): 2 blocks/CU (LDS-capped), VGPR <= 256 no-spill
//  * T14 split: next B-tile global->reg issued BEFORE compute, ds_write after
//  * xor-16 B swizzle: 2-way (free) instead of 4-way bank aliasing
//  * bijective XCD swizzle on blockIdx.x (384 % 8 == 0)
__global__ __launch_bounds__(256, 2) void k_fused(const float* __restrict__ h,
                                                  const float* __restrict__ sq,
                                                  const float* __restrict__ q,
                                                  const float* __restrict__ tempP,
                                                  float* __restrict__ cval,
                                                  int* __restrict__ cidx) {
  __shared__ float4 sA4[TM * 64];  // 32 KB, linear (broadcast-read only)
  __shared__ float4 sB4[TN * 64];  // 32 KB, xor-16 swizzled
  const int tid = threadIdx.x;
  const int trow = tid >> 5;   // 0..7 -> 4 rows each
  const int tcol = tid & 31;   // 0..31 -> 1 col per tile
  const int bx = blockIdx.x;
  const int sbx = (bx & 7) * (gridDim.x >> 3) + (bx >> 3);  // XCD-contiguous
  const int row0 = sbx * TM;
  const int split = blockIdx.y;
  const int c0 = split * CPS;
  const float T = tempP[0];

  // stage A rows once
#pragma unroll
  for (int t = 0; t < 8; ++t) {
    int fi = t * 256 + tid;
    sA4[fi] = *(const float4*)&h[(size_t)(row0 + (fi >> 6)) * D + (fi & 63) * 4];
  }
  float sqr[4];
#pragma unroll
  for (int i = 0; i < 4; i++) sqr[i] = sq[row0 + trow * 4 + i];

  float tv[4][TOPK];
  int ti[4][TOPK];
#pragma unroll
  for (int i = 0; i < 4; i++)
#pragma unroll
    for (int k = 0; k < TOPK; k++) { tv[i][k] = -3.0e38f; ti[i][k] = 0; }

  // prologue: B tile 0 -> regs
  float4 r[8];
#pragma unroll
  for (int t = 0; t < 8; ++t) {
    int fi = t * 256 + tid;
    r[t] = *(const float4*)&h[(size_t)(c0 + (fi >> 6)) * D + (fi & 63) * 4];
  }

  for (int ct = c0; ct < c0 + CPS; ct += TN) {
    __syncthreads();  // all waves done reading sB of previous tile
#pragma unroll
    for (int t = 0; t < 8; ++t) {
      int fi = t * 256 + tid;
      int col = fi >> 6, k4w = fi & 63;
      sB4[col * 64 + (k4w ^ (col & 15))] = r[t];
    }
    __syncthreads();  // sB ready
    // issue next-tile loads early: HBM latency hides under the 1024-FMA phase
    if (ct + TN < c0 + CPS) {
#pragma unroll
      for (int t = 0; t < 8; ++t) {
        int fi = t * 256 + tid;
        r[t] = *(const float4*)&h[(size_t)(ct + TN + (fi >> 6)) * D + (fi & 63) * 4];
      }
    }
    const int c = ct + tcol;
    const float sqc = sq[c];
    float qv[4];
#pragma unroll
    for (int i = 0; i < 4; i++)
      qv[i] = q[(size_t)(row0 + trow * 4 + i) * N_NODES + c];

    float4 acc[4];
#pragma unroll
    for (int i = 0; i < 4; i++) acc[i] = make_float4(0.f, 0.f, 0.f, 0.f);
#pragma unroll 4
    for (int k4 = 0; k4 < 64; ++k4) {
      const float4 b = sB4[tcol * 64 + (k4 ^ (tcol & 15))];
#pragma unroll
      for (int i = 0; i < 4; i++) {
        const float4 a = sA4[(trow * 4 + i) * 64 + k4];
        acc[i].x = fmaf(a.x, b.x, acc[i].x);
        acc[i].y = fmaf(a.y, b.y, acc[i].y);
        acc[i].z = fmaf(a.z, b.z, acc[i].z);
        acc[i].w = fmaf(a.w, b.w, acc[i].w);
      }
    }

#pragma unroll
    for (int i = 0; i < 4; i++) {
      float dot = __fadd_rn(__fadd_rn(acc[i].x, acc[i].y), __fadd_rn(acc[i].z, acc[i].w));
      float s2 = __fadd_rn(sqr[i], sqc);
      float d2 = fmaxf(__fsub_rn(s2, __fmul_rn(2.0f, dot)), 0.0f);
      float lp = -__fmul_rn(T, d2);
      float gg = logf(-logf(__fadd_rn(qv[i], 1e-8f)));
      ins4(__fsub_rn(lp, gg), c, tv[i], ti[i]);
    }
  }

  // butterfly merge across the 32 column-lanes
#pragma unroll
  for (int i = 0; i < 4; i++) {
#pragma unroll
    for (int m = 1; m < 32; m <<= 1) {
      float ov[TOPK]; int oi[TOPK];
#pragma unroll
      for (int k = 0; k < TOPK; k++) {
        ov[k] = __shfl_xor(tv[i][k], m, 32);
        oi[k] = __shfl_xor(ti[i][k], m, 32);
      }
#pragma unroll
      for (int k = 0; k < TOPK; k++) ins4tie(ov[k], oi[k], tv[i], ti[i]);
    }
  }
  if (tcol == 0) {
#pragma unroll
    for (int i = 0; i < 4; i++)
#pragma unroll
      for (int k = 0; k < TOPK; k++) {
        cval[((size_t)(row0 + trow * 4 + i) * NSPLIT + split) * TOPK + k] = tv[i][k];
        cidx[((size_t)(row0 + trow * 4 + i) * NSPLIT + split) * TOPK + k] = ti[i][k];
      }
  }
}

// ---------------- K7: merge splits, write edges + top_vals as FLOAT32 ----------
__global__ __launch_bounds__(256) void k_merge(const float* __restrict__ cval,
                                               const int* __restrict__ cidx,
                                               float* __restrict__ out_idx,
                                               float* __restrict__ out_rows,
                                               float* __restrict__ out_vals) {
  int r = blockIdx.x * blockDim.x + threadIdx.x;
  if (r >= N_NODES) return;
  float bv[TOPK];
  int bi[TOPK];
#pragma unroll
  for (int k = 0; k < TOPK; k++) { bv[k] = -3.0e38f; bi[k] = 0; }
  for (int t = 0; t < NSPLIT * TOPK; t++)
    ins4tie(cval[(size_t)r * NSPLIT * TOPK + t], cidx[(size_t)r * NSPLIT * TOPK + t], bv, bi);
#pragma unroll
  for (int k = 0; k < TOPK; k++) {
    out_idx[r * TOPK + k] = (float)bi[k];
    out_rows[r * TOPK + k] = (float)r;
    out_vals[r * TOPK + k] = bv[k];
  }
}

// ---------------- launcher ----------------
extern "C" void kernel_launch(void* const* d_in, const int* in_sizes, int n_in,
                              void* d_out, int out_size, void* d_ws, size_t ws_size,
                              hipStream_t stream) {
  const float* x = nullptr;     // 3145728
  const float* W = nullptr;     // 65536
  const float* b = nullptr;     // 256
  const float* temp = nullptr;  // 1
  const float* q = nullptr;     // 150994944
  const int* ei = nullptr;      // 393216
  for (int i = 0; i < n_in; ++i) {
    switch (in_sizes[i]) {
      case 3145728:   x = (const float*)d_in[i]; break;
      case 65536:     W = (const float*)d_in[i]; break;
      case 256:       b = (const float*)d_in[i]; break;
      case 1:         temp = (const float*)d_in[i]; break;
      case 150994944: q = (const float*)d_in[i]; break;
      case 393216:    ei = (const int*)d_in[i]; break;
      default: break;
    }
  }
  if (!x || !W || !b || !temp || !q || !ei) return;

  float* out = (float*)d_out;
  float* out_h = out;                                  // [0, 3145728)
  float* out_idx = out + (size_t)N_NODES * D;          // [3145728, 3194880)
  float* out_rows = out_idx + (size_t)N_NODES * TOPK;  // [3194880, 3244032)
  float* out_vals = out_rows + (size_t)N_NODES * TOPK; // [3244032, 3293184)

  char* ws = (char*)d_ws;
  size_t off = 0;
  auto alloc = [&](size_t bytes) {
    char* p = ws + off;
    off += (bytes + 255) & ~(size_t)255;
    return p;
  };
  float* XW = (float*)alloc((size_t)N_NODES * D * 4);
  int* deg = (int*)alloc((size_t)N_NODES * 4);
  int* rs = (int*)alloc((size_t)N_NODES * 4);
  int* cur = (int*)alloc((size_t)N_NODES * 4);
  float* dinv = (float*)alloc((size_t)N_NODES * 4);
  float* sq = (float*)alloc((size_t)N_NODES * 4);
  int* ecol = (int*)alloc((size_t)NE * 4);
  int* eeid = (int*)alloc((size_t)NE * 4);
  float* cval = (float*)alloc((size_t)N_NODES * NSPLIT * TOPK * 4);
  int* cidx = (int*)alloc((size_t)N_NODES * NSPLIT * TOPK * 4);
  if (off > ws_size) return;

  hipMemsetAsync(deg, 0, (size_t)N_NODES * 4, stream);
  hipMemsetAsync(cur, 0, (size_t)N_NODES * 4, stream);

  k_xw<<<dim3(N_NODES / 64, D / 64), 256, 0, stream>>>(x, W, XW);
  k_deg<<<NE / 256, 256, 0, stream>>>(ei, deg);
  k_scan<<<1, 256, 0, stream>>>(deg, rs, dinv);
  k_fill<<<NE / 256, 256, 0, stream>>>(ei, ei + NE, rs, cur, ecol, eeid);
  k_agg<<<N_NODES, 256, 0, stream>>>(XW, b, deg, rs, ecol, eeid, dinv, out_h, sq);
  k_fused<<<dim3(N_NODES / TM, NSPLIT), 256, 0, stream>>>(out_h, sq, q, temp, cval, cidx);
  k_merge<<<N_NODES / 256, 256, 0, stream>>>(cval, cidx, out_idx, out_rows, out_vals);
}